// Round 10
// baseline (153.919 us; speedup 1.0000x reference)
//
#include <hip/hip_runtime.h>
#include <math.h>

#define C_ 512
#define HW_ 16384
#define K_ 19
#define M_ 5
#define P_ 95
#define P2 96
#define TPX 32
#define NBLK 2048
#define HL2PI 470.49652900081467f  // 0.5 * 512 * ln(2*pi)

typedef __attribute__((ext_vector_type(8))) short short8;
typedef __attribute__((ext_vector_type(4))) int int4v;
typedef __attribute__((ext_vector_type(4))) float float4v;

// fp32 -> bf16 RNE (prep kernel only; main uses packed cvt)
static __device__ __forceinline__ short f2bf(float f) {
  unsigned u = __builtin_bit_cast(unsigned, f);
  unsigned r = (u + 0x7fffu + ((u >> 16) & 1u)) >> 16;
  return (short)r;
}

// pack 2 floats -> bf16x2 via v_cvt_pk_bf16_f32 (no builtin on gfx950)
static __device__ __forceinline__ int pk2(float a, float b) {
  int r;
  asm("v_cvt_pk_bf16_f32 %0, %1, %2" : "=v"(r) : "v"(a), "v"(b));
  return r;
}

// square a bf16x8 fragment in-register: unpack pairs, square, packed-repack
static __device__ __forceinline__ short8 sq8(short8 a) {
  int4v ai = __builtin_bit_cast(int4v, a);
  int4v ri;
#pragma unroll
  for (int j = 0; j < 4; j++) {
    unsigned u = (unsigned)ai[j];
    float lo = __builtin_bit_cast(float, u << 16);
    float hi = __builtin_bit_cast(float, u & 0xffff0000u);
    ri[j] = pk2(lo * lo, hi * hi);
  }
  return __builtin_bit_cast(short8, ri);
}

__device__ __forceinline__ float block_reduce_sum(float v, volatile float* red) {
#pragma unroll
  for (int o = 32; o; o >>= 1) v += __shfl_down(v, o);
  const int lane = threadIdx.x & 63, wv = threadIdx.x >> 6;
  if (lane == 0) red[wv] = v;
  __syncthreads();
  float r = red[0] + red[1] + red[2] + red[3];
  __syncthreads();
  return r;
}

// wbf[p][seg][c] bf16, seg stride 512, p stride 1536:
//   p<95:  S0 = iv*g^2, S1 = iv*g*beta, S2 = mu*iv*g  (iv=1/sigma^2, mu l2-normed)
//   p==95: S0 = g^2,    S1 = g*beta,    S2 = g        (norm row: gives Sum v^2)
// ctp[p*8 + {0..5}] = {ct, T1, T2, T3, T4, T5}:
//   T1=S[iv b^2], T2=S[iv g b], T3=S[iv g^2], T4=S[mu iv b], T5=S[mu iv g]
//   ct = -0.5*S[mu^2 iv] - S[log sigma] - HL2PI   (p==95: ct,T4,T5 = 0; iv->1)
__global__ __launch_bounds__(256) void prep_kernel(
    const float* __restrict__ means, const float* __restrict__ diag,
    const float* __restrict__ fg, const float* __restrict__ fb,
    short* __restrict__ wbf, float* __restrict__ ctp) {
  const int p = blockIdx.x;
  const int tid = threadIdx.x;
  __shared__ float red[4];
  if (p == P_) {  // norm row
    float t1 = 0.f, t2 = 0.f, t3 = 0.f;
#pragma unroll
    for (int t = 0; t < 2; t++) {
      int c = tid + t * 256;
      float g = fg[c], bb = fb[c];
      wbf[p * 1536 + c] = f2bf(g * g);
      wbf[p * 1536 + 512 + c] = f2bf(g * bb);
      wbf[p * 1536 + 1024 + c] = f2bf(g);
      t1 += bb * bb;
      t2 += g * bb;
      t3 += g * g;
    }
    t1 = block_reduce_sum(t1, red);
    t2 = block_reduce_sum(t2, red);
    t3 = block_reduce_sum(t3, red);
    if (tid == 0) {
      ctp[p * 8 + 0] = 0.f;
      ctp[p * 8 + 1] = t1;
      ctp[p * 8 + 2] = t2;
      ctp[p * 8 + 3] = t3;
      ctp[p * 8 + 4] = 0.f;
      ctp[p * 8 + 5] = 0.f;
    }
    return;
  }
  const float* mrow = means + (size_t)p * C_;
  const float* srow = diag + (size_t)p * C_;
  float m0 = mrow[tid], m1 = mrow[tid + 256];
  float ss = block_reduce_sum(m0 * m0 + m1 * m1, red);
  float rden = 1.f / fmaxf(sqrtf(ss), 1e-12f);  // l2_normalize(means)
  float t1 = 0.f, t2 = 0.f, t3 = 0.f, t4 = 0.f, t5 = 0.f, q3 = 0.f, ld = 0.f;
#pragma unroll
  for (int t = 0; t < 2; t++) {
    int c = tid + t * 256;
    float m = mrow[c], sg = srow[c], g = fg[c], bb = fb[c];
    float mu = m * rden;
    float iv = 1.f / (sg * sg);
    wbf[p * 1536 + c] = f2bf(iv * g * g);
    wbf[p * 1536 + 512 + c] = f2bf(iv * g * bb);
    wbf[p * 1536 + 1024 + c] = f2bf(mu * iv * g);
    t1 += iv * bb * bb;
    t2 += iv * g * bb;
    t3 += iv * g * g;
    t4 += mu * iv * bb;
    t5 += mu * iv * g;
    q3 += mu * mu * iv;
    ld += logf(sg);
  }
  t1 = block_reduce_sum(t1, red);
  t2 = block_reduce_sum(t2, red);
  t3 = block_reduce_sum(t3, red);
  t4 = block_reduce_sum(t4, red);
  t5 = block_reduce_sum(t5, red);
  q3 = block_reduce_sum(q3, red);
  ld = block_reduce_sum(ld, red);
  if (tid == 0) {
    ctp[p * 8 + 0] = -0.5f * q3 - ld - HL2PI;
    ctp[p * 8 + 1] = t1;
    ctp[p * 8 + 2] = t2;
    ctp[p * 8 + 3] = t3;
    ctp[p * 8 + 4] = t4;
    ctp[p * 8 + 5] = t5;
  }
}

// One block = 32 pixels, 256 threads (4 waves), ~37 KB LDS -> 4 blocks/CU.
// v = s*(g x) + (b - mu*s*g)  =>  q1,q2,Sum v^2 are linear combos of x-GEMMs:
//   R1 = S0.x^2, R2 = S0.x, R3 = S1.x, R4 = S2.x  (per pixel, per p-row)
// Stream phase: load x -> pack bf16 x-frags -> LDS; accumulate Sx, Sx^2.
// NO stats barrier inside the load path. x^2-frag = sq8(x-frag) at MFMA time.
// Row 95 gives Sum v^2 -> rn. Single-stage epilogue (each wave has all 4 R's).
__global__ __launch_bounds__(256, 4) void main_kernel(
    const float* __restrict__ x,
    const short* __restrict__ wbf, const float* __restrict__ ctp,
    const float* __restrict__ mg, const float* __restrict__ mb,
    float* __restrict__ out) {
  __shared__ __align__(16) char raw[32768];  // x frags; aliased as lp[32][100]
  __shared__ float red0[256], red1[256];
  __shared__ float meanA[TPX], rstdA[TPX], rnA[TPX];
  __shared__ float mean2A[TPX], rstd2A[TPX];
  __shared__ float mpr[TPX * 20];

  const int tid = threadIdx.x;
  const int px = tid & 31, part = tid >> 5;  // 8 parts x 64 channels
  const int wv = tid >> 6, lane = tid & 63;
  const int n0 = blockIdx.x * TPX;
  const int b = n0 >> 14;
  const int rem = n0 & 16383;
  const int h = rem >> 7;
  const int w0 = rem & 127;
  const int cbase = part * 64;
  const int t_ = px >> 4, lq = px & 15;
  const float* xp = x + (size_t)b * C_ * HW_ + h * 128 + w0 + px;

  // ---- Stream: load x (one HBM pass), pack bf16 -> LDS, Sx/Sx2 ----
  float xv[64];
#pragma unroll
  for (int i = 0; i < 64; i++) xv[i] = xp[(size_t)(cbase + i) * HW_];
  {
    float s1 = 0.f, s2 = 0.f;
#pragma unroll
    for (int g = 0; g < 8; g++) {
      const int c0 = cbase + g * 8;
      int4v pk;
#pragma unroll
      for (int j2 = 0; j2 < 4; j2++) {
        float a = xv[g * 8 + 2 * j2], bb = xv[g * 8 + 2 * j2 + 1];
        s1 += a + bb;
        s2 = fmaf(a, a, fmaf(bb, bb, s2));
        pk[j2] = pk2(a, bb);
      }
      *(int4v*)(raw + (((t_ * 16 + (c0 >> 5)) << 10) | (((((c0 >> 3) & 3) << 4) | lq) << 4))) = pk;
    }
    red0[part * 32 + px] = s1;
    red1[part * 32 + px] = s2;
  }
  __syncthreads();
  if (tid < 32) {
    float ss = 0.f, qq = 0.f;
#pragma unroll
    for (int i = 0; i < 8; i++) {
      ss += red0[i * 32 + tid];
      qq += red1[i * 32 + tid];
    }
    float mean = ss * (1.f / C_);
    float var = qq * (1.f / C_) - mean * mean;
    meanA[tid] = mean;
    rstdA[tid] = rsqrtf(var + 1e-5f);
  }
  __syncthreads();

  // ---- MFMA: wave = (phalf = wv&1 -> 3 p-tiles, pxt = wv>>1) ----
  const int pbase = (wv & 1) * 3;
  const int pxt = wv >> 1;
  const int lm = lane & 15, lk = lane >> 4;
  float4v a1[3] = {}, a2[3] = {}, a3[3] = {}, a4[3] = {};
  const short* wA = wbf + ((pbase * 16 + lm) * 1536 + lk * 8);
  const short* wB = wbf + (((pbase + 1) * 16 + lm) * 1536 + lk * 8);
  const short* wC = wbf + (((pbase + 2) * 16 + lm) * 1536 + lk * 8);
#pragma unroll 4
  for (int ksl = 0; ksl < 16; ksl++) {
    short8 bx = *(const short8*)(raw + pxt * 16384 + (ksl << 10) + (lane << 4));
    short8 bx2 = sq8(bx);
    short8 sA0 = *(const short8*)(wA + ksl * 32);
    short8 sA1 = *(const short8*)(wA + 512 + ksl * 32);
    short8 sA2 = *(const short8*)(wA + 1024 + ksl * 32);
    a1[0] = __builtin_amdgcn_mfma_f32_16x16x32_bf16(sA0, bx2, a1[0], 0, 0, 0);
    a2[0] = __builtin_amdgcn_mfma_f32_16x16x32_bf16(sA0, bx, a2[0], 0, 0, 0);
    a3[0] = __builtin_amdgcn_mfma_f32_16x16x32_bf16(sA1, bx, a3[0], 0, 0, 0);
    a4[0] = __builtin_amdgcn_mfma_f32_16x16x32_bf16(sA2, bx, a4[0], 0, 0, 0);
    short8 sB0 = *(const short8*)(wB + ksl * 32);
    short8 sB1 = *(const short8*)(wB + 512 + ksl * 32);
    short8 sB2 = *(const short8*)(wB + 1024 + ksl * 32);
    a1[1] = __builtin_amdgcn_mfma_f32_16x16x32_bf16(sB0, bx2, a1[1], 0, 0, 0);
    a2[1] = __builtin_amdgcn_mfma_f32_16x16x32_bf16(sB0, bx, a2[1], 0, 0, 0);
    a3[1] = __builtin_amdgcn_mfma_f32_16x16x32_bf16(sB1, bx, a3[1], 0, 0, 0);
    a4[1] = __builtin_amdgcn_mfma_f32_16x16x32_bf16(sB2, bx, a4[1], 0, 0, 0);
    short8 sC0 = *(const short8*)(wC + ksl * 32);
    short8 sC1 = *(const short8*)(wC + 512 + ksl * 32);
    short8 sC2 = *(const short8*)(wC + 1024 + ksl * 32);
    a1[2] = __builtin_amdgcn_mfma_f32_16x16x32_bf16(sC0, bx2, a1[2], 0, 0, 0);
    a2[2] = __builtin_amdgcn_mfma_f32_16x16x32_bf16(sC0, bx, a2[2], 0, 0, 0);
    a3[2] = __builtin_amdgcn_mfma_f32_16x16x32_bf16(sC1, bx, a3[2], 0, 0, 0);
    a4[2] = __builtin_amdgcn_mfma_f32_16x16x32_bf16(sC2, bx, a4[2], 0, 0, 0);
  }

  // ---- rn from norm row (p=95 lives in phalf=1 waves, i=2, lk=3, r=3) ----
  if ((wv & 1) == 1 && lk == 3) {
    const int pxx = pxt * 16 + lm;
    float mu_ = meanA[pxx], s_ = rstdA[pxx];
    float ms = mu_ * s_;
    float T1 = ctp[95 * 8 + 1], T2 = ctp[95 * 8 + 2], T3 = ctp[95 * 8 + 3];
    float sv = s_ * s_ * a1[2][3] + 2.f * s_ * a3[2][3] - 2.f * ms * s_ * a2[2][3] +
               (T1 - 2.f * ms * T2 + ms * ms * T3);
    rnA[pxx] = 1.f / fmaxf(sqrtf(sv), 1e-12f);
  }
  __syncthreads();  // all MFMA done (raw dead), rnA ready
  float* lp = (float*)raw;

  // ---- epilogue: logp = -0.5 rn^2 q1 + rn q2 + ct, single stage ----
  {
    const int pxx = pxt * 16 + lm;
    const float mu_ = meanA[pxx], s_ = rstdA[pxx], rn = rnA[pxx];
    const float ms = mu_ * s_, ss = s_ * s_, Ac = -0.5f * rn * rn;
#pragma unroll
    for (int i = 0; i < 3; i++) {
#pragma unroll
      for (int r = 0; r < 4; r++) {
        const int p = (pbase + i) * 16 + lk * 4 + r;
        const float* c6 = ctp + p * 8;
        float q1 = ss * a1[i][r] + 2.f * s_ * a3[i][r] - 2.f * ms * s_ * a2[i][r] +
                   (c6[1] - 2.f * ms * c6[2] + ms * ms * c6[3]);
        float q2 = s_ * a4[i][r] + c6[4] - ms * c6[5];
        lp[pxx * 100 + p] = fmaf(Ac, q1, fmaf(rn, q2, c6[0]));
      }
    }
  }
  __syncthreads();

  // ---- max over M ----
  for (int idx = tid; idx < TPX * K_; idx += 256) {
    const int pxx = idx / K_;
    const int k = idx - pxx * K_;
    const float* row = lp + pxx * 100 + k * M_;
    float mv = row[0];
#pragma unroll
    for (int m = 1; m < M_; m++) mv = fmaxf(mv, row[m]);
    mpr[pxx * 20 + k] = mv;
  }
  __syncthreads();
  // ---- LN over K (two-pass: values ~ -470, var ~ 1e-3) ----
  if (tid < 32) {
    float ss = 0.f;
    for (int k = 0; k < K_; k++) ss += mpr[tid * 20 + k];
    float m2 = ss * (1.f / K_);
    float qq = 0.f;
    for (int k = 0; k < K_; k++) {
      float d = mpr[tid * 20 + k] - m2;
      qq += d * d;
    }
    mean2A[tid] = m2;
    rstd2A[tid] = rsqrtf(qq * (1.f / K_) + 1e-5f);
  }
  __syncthreads();
  // ---- coalesced store (B,K,H,W) ----
  float* obase = out + ((size_t)(b * K_) * 128 + h) * 128 + w0;
  for (int idx = tid; idx < TPX * K_; idx += 256) {
    const int k = idx >> 5, pxx = idx & 31;
    float v = fmaf((mpr[pxx * 20 + k] - mean2A[pxx]) * rstd2A[pxx], mg[k], mb[k]);
    obase[(size_t)k * HW_ + pxx] = v;
  }
}

extern "C" void kernel_launch(void* const* d_in, const int* in_sizes, int n_in,
                              void* d_out, int out_size, void* d_ws, size_t ws_size,
                              hipStream_t stream) {
  const float* x = (const float*)d_in[0];
  const float* means = (const float*)d_in[1];
  const float* diag = (const float*)d_in[2];
  const float* fg = (const float*)d_in[3];
  const float* fb = (const float*)d_in[4];
  const float* mg = (const float*)d_in[5];
  const float* mb = (const float*)d_in[6];
  float* out = (float*)d_out;

  short* wbf = (short*)d_ws;                                       // 96*1536*2 B
  float* ctp = (float*)((char*)d_ws + (size_t)P2 * 1536 * 2);      // +96*8*4 B

  prep_kernel<<<P2, 256, 0, stream>>>(means, diag, fg, fb, wbf, ctp);
  main_kernel<<<NBLK, 256, 0, stream>>>(x, wbf, ctp, mg, mb, out);
}

// Round 11
// 81.096 us; speedup vs baseline: 1.8980x; 1.8980x over previous
//
#include <hip/hip_runtime.h>
#include <math.h>

#define C_ 512
#define HW_ 16384
#define K_ 19
#define M_ 5
#define P_ 95
#define P2 96
#define TPX 32
#define NBLK 2048
#define HL2PI 470.49652900081467f  // 0.5 * 512 * ln(2*pi)

typedef __attribute__((ext_vector_type(8))) short short8;
typedef __attribute__((ext_vector_type(4))) int int4v;
typedef __attribute__((ext_vector_type(4))) float float4v;

// fp32 -> bf16 RNE (prep kernel only; main uses packed cvt)
static __device__ __forceinline__ short f2bf(float f) {
  unsigned u = __builtin_bit_cast(unsigned, f);
  unsigned r = (u + 0x7fffu + ((u >> 16) & 1u)) >> 16;
  return (short)r;
}

// pack 2 floats -> bf16x2 via v_cvt_pk_bf16_f32 (no builtin on gfx950)
static __device__ __forceinline__ int pk2(float a, float b) {
  int r;
  asm("v_cvt_pk_bf16_f32 %0, %1, %2" : "=v"(r) : "v"(a), "v"(b));
  return r;
}

// square a bf16x8 fragment in-register: unpack pairs, square, packed-repack
static __device__ __forceinline__ short8 sq8(short8 a) {
  int4v ai = __builtin_bit_cast(int4v, a);
  int4v ri;
#pragma unroll
  for (int j = 0; j < 4; j++) {
    unsigned u = (unsigned)ai[j];
    float lo = __builtin_bit_cast(float, u << 16);
    float hi = __builtin_bit_cast(float, u & 0xffff0000u);
    ri[j] = pk2(lo * lo, hi * hi);
  }
  return __builtin_bit_cast(short8, ri);
}

__device__ __forceinline__ float block_reduce_sum(float v, volatile float* red) {
#pragma unroll
  for (int o = 32; o; o >>= 1) v += __shfl_down(v, o);
  const int lane = threadIdx.x & 63, wv = threadIdx.x >> 6;
  if (lane == 0) red[wv] = v;
  __syncthreads();
  float r = red[0] + red[1] + red[2] + red[3];
  __syncthreads();
  return r;
}

// One block per prototype p. wbf[p][k] bf16 row-major [96][1024]:
//   k <  512: inv_var[c];  k >= 512: mu[c]*inv_var[c]
// cterm[p] = -0.5*q3 - logdet - HL2PI  (fp32)
__global__ __launch_bounds__(256) void prep_kernel(
    const float* __restrict__ means, const float* __restrict__ diag,
    short* __restrict__ wbf, float* __restrict__ cterm) {
  const int p = blockIdx.x;
  const int tid = threadIdx.x;
  __shared__ float red[4];
  if (p >= P_) {  // zero-pad row 95: contributes 0, never selected in max
    for (int c = tid; c < C_; c += 256) {
      wbf[p * 1024 + c] = 0;
      wbf[p * 1024 + 512 + c] = 0;
    }
    if (tid == 0) cterm[p] = 0.f;
    return;
  }
  const float* mrow = means + (size_t)p * C_;
  const float* srow = diag + (size_t)p * C_;
  float m0 = mrow[tid], m1 = mrow[tid + 256];
  float ss = block_reduce_sum(m0 * m0 + m1 * m1, red);
  float rden = 1.f / fmaxf(sqrtf(ss), 1e-12f);  // l2_normalize(means)
  float q3 = 0.f, ld = 0.f;
#pragma unroll
  for (int t = 0; t < 2; t++) {
    int c = tid + t * 256;
    float m = mrow[c], s = srow[c];
    float mu = m * rden;
    float iv = 1.f / (s * s);
    wbf[p * 1024 + c] = f2bf(iv);
    wbf[p * 1024 + 512 + c] = f2bf(mu * iv);
    q3 += mu * mu * iv;
    ld += logf(s);
  }
  q3 = block_reduce_sum(q3, red);
  ld = block_reduce_sum(ld, red);
  if (tid == 0) cterm[p] = -0.5f * q3 - ld - HL2PI;
}

// One block = 32 pixels, 256 threads (4 waves). LDS ~18 KB -> 8 blocks/CU.
// C processed in two 256-channel halves through a 16 KiB u buffer:
//   pack half (v bf16 frags, x re-read from L2) -> MFMA half (acc carries).
// u half-layout: 16 blocks of 1 KiB = [t_ (2)][ks_local (8)]; elem (c, px) at
// ((t_*8+ks)<<10) | (((c>>3)&3)<<8) | ((px&15)<<4) | ((c&7)<<1), ks=(c>>5)&7.
// khalf=0 waves square the v-frag in-register (q1); khalf=1 use v (q2).
// red0 aliases raw[0:1024] (phase-A only); lp/mpr alias raw after MFMA.
__global__ __launch_bounds__(256) void main_kernel(
    const float* __restrict__ x,
    const float* __restrict__ fg, const float* __restrict__ fb,
    const float* __restrict__ mg, const float* __restrict__ mb,
    const short* __restrict__ wbf, const float* __restrict__ cterm,
    float* __restrict__ out) {
  __shared__ __align__(16) char raw[16384];  // u half; aliases: red0, lp, mpr
  __shared__ float red1[256];
  __shared__ float meanA[TPX], rstdA[TPX], rnA[TPX], rn2A[TPX];
  __shared__ float mean2A[TPX], rstd2A[TPX];

  const int tid = threadIdx.x;
  const int px = tid & 31, part = tid >> 5;  // 8 parts
  const int wv = tid >> 6, lane = tid & 63;
  const int n0 = blockIdx.x * TPX;
  const int b = n0 >> 14;
  const int rem = n0 & 16383;
  const int h = rem >> 7;
  const int w0 = rem & 127;
  const int t_ = px >> 4, lq = px & 15;
  const float* xp = x + (size_t)b * C_ * HW_ + h * 128 + w0 + px;

  // ---- Phase A: stream x (HBM), LN stats only (no caching, no packing) ----
  float* red0 = (float*)raw;
  {
    float s = 0.f, q = 0.f;
#pragma unroll 1
    for (int g = 0; g < 8; g++) {
      float xv[8];
#pragma unroll
      for (int j = 0; j < 8; j++) xv[j] = xp[(size_t)(part * 64 + g * 8 + j) * HW_];
#pragma unroll
      for (int j = 0; j < 8; j++) {
        s += xv[j];
        q = fmaf(xv[j], xv[j], q);
      }
    }
    red0[tid] = s;
    red1[tid] = q;
  }
  __syncthreads();
  if (tid < 32) {
    float ss = 0.f, qq = 0.f;
#pragma unroll
    for (int i = 0; i < 8; i++) {
      ss += red0[i * 32 + tid];
      qq += red1[i * 32 + tid];
    }
    float mean = ss * (1.f / C_);
    float var = qq * (1.f / C_) - mean * mean;
    meanA[tid] = mean;
    rstdA[tid] = rsqrtf(var + 1e-5f);
  }
  __syncthreads();

  // ---- Two halves: pack v (x from L2) -> MFMA (accumulate) ----
  const int pbase = (wv & 1) * 3;
  const int khalf = wv >> 1;  // 0: q1 (sq8(v), A=iv), 1: q2 (v, A=mu*iv)
  const int lm = lane & 15, lk = lane >> 4;
  float4v acc[3][2] = {{}, {}, {}};
  const short* wrow = wbf + (((pbase * 16 + lm) << 10) + (khalf << 9) + (lk << 3));
  float s2 = 0.f;
  const float mean = meanA[px], rstd = rstdA[px];

#pragma unroll 1
  for (int half = 0; half < 2; half++) {
    // pack phase: this thread covers 32 channels of this half
#pragma unroll
    for (int j8 = 0; j8 < 4; j8++) {
      const int c0 = half * 256 + part * 32 + j8 * 8;
      float xv[8];
#pragma unroll
      for (int j = 0; j < 8; j++) xv[j] = xp[(size_t)(c0 + j) * HW_];
      float vv[8];
#pragma unroll
      for (int j = 0; j < 8; j++) {
        float v = fmaf((xv[j] - mean) * rstd, fg[c0 + j], fb[c0 + j]);
        s2 = fmaf(v, v, s2);
        vv[j] = v;
      }
      int4v pk;
#pragma unroll
      for (int j2 = 0; j2 < 4; j2++) pk[j2] = pk2(vv[2 * j2], vv[2 * j2 + 1]);
      const int ksl = (c0 >> 5) & 7;
      *(int4v*)(raw + (((t_ * 8 + ksl) << 10) | (((c0 >> 3) & 3) << 8) | (lq << 4))) = pk;
    }
    __syncthreads();  // u half ready

    // MFMA phase: 8 k-slices of this half
#pragma unroll 4
    for (int ksl = 0; ksl < 8; ksl++) {
      const int kk = half * 8 + ksl;
      short8 a0 = *(const short8*)(wrow + kk * 32);
      short8 a1 = *(const short8*)(wrow + 16384 + kk * 32);
      short8 a2 = *(const short8*)(wrow + 32768 + kk * 32);
      short8 b0 = *(const short8*)(raw + ((ksl << 10) | (lane << 4)));
      short8 b1 = *(const short8*)(raw + (((8 + ksl) << 10) | (lane << 4)));
      if (khalf == 0) {  // wave-uniform branch
        b0 = sq8(b0);
        b1 = sq8(b1);
      }
      acc[0][0] = __builtin_amdgcn_mfma_f32_16x16x32_bf16(a0, b0, acc[0][0], 0, 0, 0);
      acc[0][1] = __builtin_amdgcn_mfma_f32_16x16x32_bf16(a0, b1, acc[0][1], 0, 0, 0);
      acc[1][0] = __builtin_amdgcn_mfma_f32_16x16x32_bf16(a1, b0, acc[1][0], 0, 0, 0);
      acc[1][1] = __builtin_amdgcn_mfma_f32_16x16x32_bf16(a1, b1, acc[1][1], 0, 0, 0);
      acc[2][0] = __builtin_amdgcn_mfma_f32_16x16x32_bf16(a2, b0, acc[2][0], 0, 0, 0);
      acc[2][1] = __builtin_amdgcn_mfma_f32_16x16x32_bf16(a2, b1, acc[2][1], 0, 0, 0);
    }
    __syncthreads();  // raw dead (next half overwrites / epilogue aliases)
  }

  // ---- rn reduction (Sum v^2 accumulated across both halves) ----
  red1[tid] = s2;
  __syncthreads();
  if (tid < 32) {
    float ss = 0.f;
#pragma unroll
    for (int i = 0; i < 8; i++) ss += red1[i * 32 + tid];
    float rn = 1.f / fmaxf(sqrtf(ss), 1e-12f);  // l2_normalize folded into epilogue
    rnA[tid] = rn;
    rn2A[tid] = rn * rn;
  }
  __syncthreads();

  float* lp = (float*)raw;            // [32][100] = 12800 B
  float* mpr = (float*)(raw + 12800);  // [32][20] = 2560 B

  // stage 1: khalf0 waves write -0.5*rn2*q1 + ct
  if (khalf == 0) {
#pragma unroll
    for (int i = 0; i < 3; i++) {
      const int prow = (pbase + i) * 16 + lk * 4;
#pragma unroll
      for (int r = 0; r < 4; r++) {
        const float ct = cterm[prow + r];
#pragma unroll
        for (int t2 = 0; t2 < 2; t2++) {
          const int pxx = t2 * 16 + lm;
          lp[pxx * 100 + prow + r] = fmaf(-0.5f * rn2A[pxx], acc[i][t2][r], ct);
        }
      }
    }
  }
  __syncthreads();
  // stage 2: khalf1 waves add rn*q2
  if (khalf == 1) {
#pragma unroll
    for (int i = 0; i < 3; i++) {
      const int prow = (pbase + i) * 16 + lk * 4;
#pragma unroll
      for (int r = 0; r < 4; r++) {
#pragma unroll
        for (int t2 = 0; t2 < 2; t2++) {
          const int pxx = t2 * 16 + lm;
          lp[pxx * 100 + prow + r] += rnA[pxx] * acc[i][t2][r];
        }
      }
    }
  }
  __syncthreads();

  // ---- max over M ----
  for (int idx = tid; idx < TPX * K_; idx += 256) {
    const int pxx = idx / K_;
    const int k = idx - pxx * K_;
    const float* row = lp + pxx * 100 + k * M_;
    float mv = row[0];
#pragma unroll
    for (int m = 1; m < M_; m++) mv = fmaxf(mv, row[m]);
    mpr[pxx * 20 + k] = mv;
  }
  __syncthreads();
  // ---- LN over K (two-pass: values ~ -470, var ~ 1e-3) ----
  if (tid < 32) {
    float ss = 0.f;
    for (int k = 0; k < K_; k++) ss += mpr[tid * 20 + k];
    float m2 = ss * (1.f / K_);
    float qq = 0.f;
    for (int k = 0; k < K_; k++) {
      float d = mpr[tid * 20 + k] - m2;
      qq += d * d;
    }
    mean2A[tid] = m2;
    rstd2A[tid] = rsqrtf(qq * (1.f / K_) + 1e-5f);
  }
  __syncthreads();
  // ---- coalesced store (B,K,H,W) ----
  float* obase = out + ((size_t)(b * K_) * 128 + h) * 128 + w0;
  for (int idx = tid; idx < TPX * K_; idx += 256) {
    const int k = idx >> 5, pxx = idx & 31;
    float v = fmaf((mpr[pxx * 20 + k] - mean2A[pxx]) * rstd2A[pxx], mg[k], mb[k]);
    obase[(size_t)k * HW_ + pxx] = v;
  }
}

extern "C" void kernel_launch(void* const* d_in, const int* in_sizes, int n_in,
                              void* d_out, int out_size, void* d_ws, size_t ws_size,
                              hipStream_t stream) {
  const float* x = (const float*)d_in[0];
  const float* means = (const float*)d_in[1];
  const float* diag = (const float*)d_in[2];
  const float* fg = (const float*)d_in[3];
  const float* fb = (const float*)d_in[4];
  const float* mg = (const float*)d_in[5];
  const float* mb = (const float*)d_in[6];
  float* out = (float*)d_out;

  short* wbf = (short*)d_ws;                                     // 96*1024*2 B
  float* cterm = (float*)((char*)d_ws + (size_t)P2 * 1024 * 2);  // +96*4 B

  prep_kernel<<<P2, 256, 0, stream>>>(means, diag, wbf, cterm);
  main_kernel<<<NBLK, 256, 0, stream>>>(x, fg, fb, mg, mb, wbf, cterm, out);
}

// Round 12
// 69.443 us; speedup vs baseline: 2.2165x; 1.1678x over previous
//
#include <hip/hip_runtime.h>
#include <math.h>

#define C_ 512
#define HW_ 16384
#define K_ 19
#define M_ 5
#define P_ 95
#define P2 96
#define TPX 32
#define NBLK 2048
#define HL2PI 470.49652900081467f  // 0.5 * 512 * ln(2*pi)

typedef __attribute__((ext_vector_type(8))) short short8;
typedef __attribute__((ext_vector_type(4))) int int4v;
typedef __attribute__((ext_vector_type(4))) float float4v;

// fp32 -> bf16 RNE (prep kernel only; main uses packed cvt)
static __device__ __forceinline__ short f2bf(float f) {
  unsigned u = __builtin_bit_cast(unsigned, f);
  unsigned r = (u + 0x7fffu + ((u >> 16) & 1u)) >> 16;
  return (short)r;
}
static __device__ __forceinline__ float bf2f(short s) {
  return __builtin_bit_cast(float, ((unsigned)(unsigned short)s) << 16);
}

// pack 2 floats -> bf16x2 via v_cvt_pk_bf16_f32 (no builtin on gfx950)
static __device__ __forceinline__ int pk2(float a, float b) {
  int r;
  asm("v_cvt_pk_bf16_f32 %0, %1, %2" : "=v"(r) : "v"(a), "v"(b));
  return r;
}

// square a bf16x8 fragment in-register: unpack pairs, square, packed-repack
static __device__ __forceinline__ short8 sq8(short8 a) {
  int4v ai = __builtin_bit_cast(int4v, a);
  int4v ri;
#pragma unroll
  for (int j = 0; j < 4; j++) {
    unsigned u = (unsigned)ai[j];
    float lo = __builtin_bit_cast(float, u << 16);
    float hi = __builtin_bit_cast(float, u & 0xffff0000u);
    ri[j] = pk2(lo * lo, hi * hi);
  }
  return __builtin_bit_cast(short8, ri);
}

__device__ __forceinline__ float block_reduce_sum(float v, volatile float* red) {
#pragma unroll
  for (int o = 32; o; o >>= 1) v += __shfl_down(v, o);
  const int lane = threadIdx.x & 63, wv = threadIdx.x >> 6;
  if (lane == 0) red[wv] = v;
  __syncthreads();
  float r = red[0] + red[1] + red[2] + red[3];
  __syncthreads();
  return r;
}

// One block per prototype p. wbf[p][k] bf16 row-major [96][1024]:
//   k <  512: inv_var[c];  k >= 512: mu[c]*inv_var[c]
// cterm[p] = -0.5*q3 - logdet - HL2PI  (fp32)
__global__ __launch_bounds__(256) void prep_kernel(
    const float* __restrict__ means, const float* __restrict__ diag,
    short* __restrict__ wbf, float* __restrict__ cterm) {
  const int p = blockIdx.x;
  const int tid = threadIdx.x;
  __shared__ float red[4];
  if (p >= P_) {  // zero-pad row 95: contributes 0, never selected in max
    for (int c = tid; c < C_; c += 256) {
      wbf[p * 1024 + c] = 0;
      wbf[p * 1024 + 512 + c] = 0;
    }
    if (tid == 0) cterm[p] = 0.f;
    return;
  }
  const float* mrow = means + (size_t)p * C_;
  const float* srow = diag + (size_t)p * C_;
  float m0 = mrow[tid], m1 = mrow[tid + 256];
  float ss = block_reduce_sum(m0 * m0 + m1 * m1, red);
  float rden = 1.f / fmaxf(sqrtf(ss), 1e-12f);  // l2_normalize(means)
  float q3 = 0.f, ld = 0.f;
#pragma unroll
  for (int t = 0; t < 2; t++) {
    int c = tid + t * 256;
    float m = mrow[c], s = srow[c];
    float mu = m * rden;
    float iv = 1.f / (s * s);
    wbf[p * 1024 + c] = f2bf(iv);
    wbf[p * 1024 + 512 + c] = f2bf(mu * iv);
    q3 += mu * mu * iv;
    ld += logf(s);
  }
  q3 = block_reduce_sum(q3, red);
  ld = block_reduce_sum(ld, red);
  if (tid == 0) cterm[p] = -0.5f * q3 - ld - HL2PI;
}

// One block = 32 pixels, 256 threads (4 waves).
// Phase A: thread (cg=tid>>3, q=tid&7) loads 16 float4 along W (channels
// cg*16..+15, pixel quad q*4..+3) -> 24 VMEM instr/thread total (was 128).
// Component transpose in-register: chunk (8 consecutive c, one px) packed bf16
// into LDS at blk = (q>>2)*16 + (cg>>1), slot = (hc*4+r)*8 + (q&3)*2 + (cg&1).
// Read side (MFMA B-frag, lane l): slotR = (((l>>4)&1)*4 + (l&3))*8 +
// ((l>>2)&3)*2 + ((l>>5)&1)  -- bijective in l, bank-floor on both sides.
// Phase B: in-place LDS RMW x->v (own bytes only). Stats/Sumv^2: shfl over cg.
__global__ __launch_bounds__(256) void main_kernel(
    const float* __restrict__ x,
    const float* __restrict__ fg, const float* __restrict__ fb,
    const float* __restrict__ mg, const float* __restrict__ mb,
    const short* __restrict__ wbf, const float* __restrict__ cterm,
    float* __restrict__ out) {
  __shared__ __align__(16) char raw[32768];  // x/v frags; aliased as lp[32][100]
  __shared__ float redS[128], redQ[128];     // 32 slots x float4
  __shared__ float meanA[TPX], rstdA[TPX], rnA[TPX], rn2A[TPX];
  __shared__ float mean2A[TPX], rstd2A[TPX];
  __shared__ float mpr[TPX * 20];

  const int tid = threadIdx.x;
  const int wv = tid >> 6, lane = tid & 63;
  const int cg = tid >> 3, q = tid & 7;  // channel group (16c), pixel quad
  const int n0 = blockIdx.x * TPX;
  const int b = n0 >> 14;
  const int rem = n0 & 16383;
  const int h = rem >> 7;
  const int w0 = rem & 127;
  const int c16 = cg * 16;
  const int blkw = (q >> 2) * 16 + (cg >> 1);
  const int sbase = (q & 3) * 2 + (cg & 1);
  const float* xp4 = x + (size_t)b * C_ * HW_ + h * 128 + w0 + q * 4;

  // ---- Phase A: float4 loads, stats accumulate, bf16 x-frags -> LDS ----
  float4v s4 = {0.f, 0.f, 0.f, 0.f}, q4 = {0.f, 0.f, 0.f, 0.f};
#pragma unroll
  for (int hc = 0; hc < 2; hc++) {
    float4v xq[8];
#pragma unroll
    for (int i = 0; i < 8; i++)
      xq[i] = *(const float4v*)(xp4 + (size_t)(c16 + hc * 8 + i) * HW_);
#pragma unroll
    for (int i = 0; i < 8; i++) {
      s4 += xq[i];
      q4 += xq[i] * xq[i];
    }
#pragma unroll
    for (int r = 0; r < 4; r++) {
      int4v pk;
#pragma unroll
      for (int j2 = 0; j2 < 4; j2++) pk[j2] = pk2(xq[2 * j2][r], xq[2 * j2 + 1][r]);
      *(int4v*)(raw + blkw * 1024 + ((hc * 4 + r) * 8 + sbase) * 16) = pk;
    }
  }
  // wave reduce over cg (lanes stride 8), then cross-wave via 1KB LDS
#pragma unroll
  for (int o = 8; o < 64; o <<= 1) {
#pragma unroll
    for (int c = 0; c < 4; c++) {
      s4[c] += __shfl_down(s4[c], o);
      q4[c] += __shfl_down(q4[c], o);
    }
  }
  if (lane < 8) {
    *(float4v*)(redS + (wv * 8 + lane) * 4) = s4;
    *(float4v*)(redQ + (wv * 8 + lane) * 4) = q4;
  }
  __syncthreads();
  if (tid < 32) {  // px = tid: q' = tid>>2, comp = tid&3
    float ss = 0.f, qq = 0.f;
#pragma unroll
    for (int w = 0; w < 4; w++) {
      ss += redS[(w * 8 + (tid >> 2)) * 4 + (tid & 3)];
      qq += redQ[(w * 8 + (tid >> 2)) * 4 + (tid & 3)];
    }
    float mean = ss * (1.f / C_);
    float var = qq * (1.f / C_) - mean * mean;
    meanA[tid] = mean;
    rstdA[tid] = rsqrtf(var + 1e-5f);
  }
  __syncthreads();

  // ---- Phase B: in-place LDS RMW x -> v = LN(x)*g+b; accumulate Sum v^2 ----
  {
    float fga[16], fba[16];
#pragma unroll
    for (int i = 0; i < 4; i++) {
      *(float4v*)(fga + i * 4) = *(const float4v*)(fg + c16 + i * 4);
      *(float4v*)(fba + i * 4) = *(const float4v*)(fb + c16 + i * 4);
    }
    const float4v mean4 = *(const float4v*)(meanA + q * 4);
    const float4v rstd4 = *(const float4v*)(rstdA + q * 4);
    float4v s2 = {0.f, 0.f, 0.f, 0.f};
#pragma unroll
    for (int hc = 0; hc < 2; hc++) {
#pragma unroll
      for (int r = 0; r < 4; r++) {
        char* ad = raw + blkw * 1024 + ((hc * 4 + r) * 8 + sbase) * 16;
        short8 xc = *(short8*)ad;
        const float m = mean4[r], sd = rstd4[r];
        float vv[8];
#pragma unroll
        for (int j = 0; j < 8; j++) {
          float v = fmaf((bf2f(xc[j]) - m) * sd, fga[hc * 8 + j], fba[hc * 8 + j]);
          s2[r] = fmaf(v, v, s2[r]);
          vv[j] = v;
        }
        int4v pk;
#pragma unroll
        for (int j2 = 0; j2 < 4; j2++) pk[j2] = pk2(vv[2 * j2], vv[2 * j2 + 1]);
        *(int4v*)ad = pk;
      }
    }
#pragma unroll
    for (int o = 8; o < 64; o <<= 1) {
#pragma unroll
      for (int c = 0; c < 4; c++) s2[c] += __shfl_down(s2[c], o);
    }
    if (lane < 8) *(float4v*)(redS + (wv * 8 + lane) * 4) = s2;
  }
  __syncthreads();
  if (tid < 32) {
    float ss = 0.f;
#pragma unroll
    for (int w = 0; w < 4; w++) ss += redS[(w * 8 + (tid >> 2)) * 4 + (tid & 3)];
    float rn = 1.f / fmaxf(sqrtf(ss), 1e-12f);  // l2_normalize folded into epilogue
    rnA[tid] = rn;
    rn2A[tid] = rn * rn;
  }
  __syncthreads();

  // ---- MFMA: wave = (khalf = wv>>1, phalf = wv&1), 3 p-tiles x 2 px-tiles ----
  const int pbase = (wv & 1) * 3;
  const int khalf = wv >> 1;
  const int lm = lane & 15, lk = lane >> 4;
  const int slotR =
      ((((lane >> 4) & 1) * 4 + (lane & 3)) * 8 + ((lane >> 2) & 3) * 2 + ((lane >> 5) & 1)) * 16;
  float4v acc[3][2] = {{}, {}, {}};
  const short* wrow = wbf + (((pbase * 16 + lm) << 10) + (khalf << 9) + (lk << 3));
#pragma unroll 4
  for (int ksl = 0; ksl < 16; ksl++) {
    short8 a0 = *(const short8*)(wrow + ksl * 32);
    short8 a1 = *(const short8*)(wrow + 16384 + ksl * 32);
    short8 a2 = *(const short8*)(wrow + 32768 + ksl * 32);
    short8 b0 = *(const short8*)(raw + ksl * 1024 + slotR);
    short8 b1 = *(const short8*)(raw + (16 + ksl) * 1024 + slotR);
    if (khalf == 0) {  // wave-uniform branch
      b0 = sq8(b0);
      b1 = sq8(b1);
    }
    acc[0][0] = __builtin_amdgcn_mfma_f32_16x16x32_bf16(a0, b0, acc[0][0], 0, 0, 0);
    acc[0][1] = __builtin_amdgcn_mfma_f32_16x16x32_bf16(a0, b1, acc[0][1], 0, 0, 0);
    acc[1][0] = __builtin_amdgcn_mfma_f32_16x16x32_bf16(a1, b0, acc[1][0], 0, 0, 0);
    acc[1][1] = __builtin_amdgcn_mfma_f32_16x16x32_bf16(a1, b1, acc[1][1], 0, 0, 0);
    acc[2][0] = __builtin_amdgcn_mfma_f32_16x16x32_bf16(a2, b0, acc[2][0], 0, 0, 0);
    acc[2][1] = __builtin_amdgcn_mfma_f32_16x16x32_bf16(a2, b1, acc[2][1], 0, 0, 0);
  }
  __syncthreads();  // u dead; alias raw as lp[32][100]
  float* lp = (float*)raw;

  // stage 1: khalf0 waves write -0.5*rn2*q1 + ct
  if (khalf == 0) {
#pragma unroll
    for (int i = 0; i < 3; i++) {
      const int prow = (pbase + i) * 16 + lk * 4;
#pragma unroll
      for (int r = 0; r < 4; r++) {
        const float ct = cterm[prow + r];
#pragma unroll
        for (int t2 = 0; t2 < 2; t2++) {
          const int pxx = t2 * 16 + lm;
          lp[pxx * 100 + prow + r] = fmaf(-0.5f * rn2A[pxx], acc[i][t2][r], ct);
        }
      }
    }
  }
  __syncthreads();
  // stage 2: khalf1 waves add rn*q2
  if (khalf == 1) {
#pragma unroll
    for (int i = 0; i < 3; i++) {
      const int prow = (pbase + i) * 16 + lk * 4;
#pragma unroll
      for (int r = 0; r < 4; r++) {
#pragma unroll
        for (int t2 = 0; t2 < 2; t2++) {
          const int pxx = t2 * 16 + lm;
          lp[pxx * 100 + prow + r] += rnA[pxx] * acc[i][t2][r];
        }
      }
    }
  }
  __syncthreads();

  // ---- max over M ----
  for (int idx = tid; idx < TPX * K_; idx += 256) {
    const int pxx = idx / K_;
    const int k = idx - pxx * K_;
    const float* row = lp + pxx * 100 + k * M_;
    float mv = row[0];
#pragma unroll
    for (int m = 1; m < M_; m++) mv = fmaxf(mv, row[m]);
    mpr[pxx * 20 + k] = mv;
  }
  __syncthreads();
  // ---- LN over K (two-pass: values ~ -470, var ~ 1e-3) ----
  if (tid < 32) {
    float ss = 0.f;
    for (int k = 0; k < K_; k++) ss += mpr[tid * 20 + k];
    float m2 = ss * (1.f / K_);
    float qq = 0.f;
    for (int k = 0; k < K_; k++) {
      float d = mpr[tid * 20 + k] - m2;
      qq += d * d;
    }
    mean2A[tid] = m2;
    rstd2A[tid] = rsqrtf(qq * (1.f / K_) + 1e-5f);
  }
  __syncthreads();
  // ---- coalesced store (B,K,H,W) ----
  float* obase = out + ((size_t)(b * K_) * 128 + h) * 128 + w0;
  for (int idx = tid; idx < TPX * K_; idx += 256) {
    const int k = idx >> 5, pxx = idx & 31;
    float v = fmaf((mpr[pxx * 20 + k] - mean2A[pxx]) * rstd2A[pxx], mg[k], mb[k]);
    obase[(size_t)k * HW_ + pxx] = v;
  }
}

extern "C" void kernel_launch(void* const* d_in, const int* in_sizes, int n_in,
                              void* d_out, int out_size, void* d_ws, size_t ws_size,
                              hipStream_t stream) {
  const float* x = (const float*)d_in[0];
  const float* means = (const float*)d_in[1];
  const float* diag = (const float*)d_in[2];
  const float* fg = (const float*)d_in[3];
  const float* fb = (const float*)d_in[4];
  const float* mg = (const float*)d_in[5];
  const float* mb = (const float*)d_in[6];
  float* out = (float*)d_out;

  short* wbf = (short*)d_ws;                                     // 96*1024*2 B
  float* cterm = (float*)((char*)d_ws + (size_t)P2 * 1024 * 2);  // +96*4 B

  prep_kernel<<<P2, 256, 0, stream>>>(means, diag, wbf, cterm);
  main_kernel<<<NBLK, 256, 0, stream>>>(x, fg, fb, mg, mb, wbf, cterm, out);
}